// Round 3
// baseline (4760.175 us; speedup 1.0000x reference)
//
#include <hip/hip_runtime.h>
#include <math.h>

#define L0_TOK 365
#define L1_TOK 366
#define L_TOT  732   // 365 + 366 + 1
#define NH     32
#define NTHREADS 256
#define XSTR   17    // words per token row (16 bf16x2 data + 1 pad; 17 coprime 32 -> 2-way max)

__device__ __forceinline__ unsigned pack_bf16x2(float a, float b) {
    unsigned ua = __float_as_uint(a), ub = __float_as_uint(b);
    ua = (ua + 0x7fffu + ((ua >> 16) & 1u)) >> 16;
    ub = (ub + 0x7fffu + ((ub >> 16) & 1u)) >> 16;
    return ua | (ub << 16);
}
__device__ __forceinline__ float bf_lo(unsigned w) { return __uint_as_float(w << 16); }
__device__ __forceinline__ float bf_hi(unsigned w) { return __uint_as_float(w & 0xffff0000u); }

// Compute the embedded token vector x[32] for token l of batch b.
__device__ __forceinline__ void embed_token(
    int b, int l,
    const float* __restrict__ x0, const float* __restrict__ x1,
    const float* __restrict__ pos0, const float* __restrict__ pos1,
    const float* __restrict__ xcT,
    const float* __restrict__ e0w1, const float* __restrict__ e0b1,
    const float* __restrict__ e0w2, const float* __restrict__ e0b2,
    const float* __restrict__ e1w1, const float* __restrict__ e1b1,
    const float* __restrict__ e1w2, const float* __restrict__ e1b2,
    const float* __restrict__ ecw1, const float* __restrict__ ecb1,
    const float* __restrict__ ecw2, const float* __restrict__ ecb2,
    float x[NH])
{
    float h[NH];
    if (l < L0_TOK) {
        float in[8];
        const float4* p = (const float4*)(x0 + ((size_t)b * L0_TOK + l) * 8);
        float4 v0 = p[0], v1 = p[1];
        in[0]=v0.x; in[1]=v0.y; in[2]=v0.z; in[3]=v0.w;
        in[4]=v1.x; in[5]=v1.y; in[6]=v1.z; in[7]=v1.w;
        #pragma unroll
        for (int o = 0; o < NH; o++) {
            float a = e0b1[o];
            #pragma unroll
            for (int i = 0; i < 8; i++) a = fmaf(e0w1[o * 8 + i], in[i], a);
            h[o] = fmaxf(a, 0.f);
        }
        #pragma unroll
        for (int o = 0; o < NH; o++) {
            float a = e0b2[o];
            #pragma unroll
            for (int j = 0; j < NH; j++) a = fmaf(e0w2[o * NH + j], h[j], a);
            x[o] = a;
        }
        float pv = pos0[(size_t)b * L0_TOK + l];
        #pragma unroll
        for (int i = 0; i < NH / 2; i++) {
            float w = 3.14159265358979323846f / (float)(i + 1);
            float ang = pv * w;
            x[2 * i]     += __sinf(ang);
            x[2 * i + 1] += __cosf(ang);
        }
    } else if (l < L0_TOK + L1_TOK) {
        int ll = l - L0_TOK;
        float in[16];
        const float4* p = (const float4*)(x1 + ((size_t)b * L1_TOK + ll) * 16);
        #pragma unroll
        for (int q = 0; q < 4; q++) {
            float4 v = p[q];
            in[4*q+0]=v.x; in[4*q+1]=v.y; in[4*q+2]=v.z; in[4*q+3]=v.w;
        }
        #pragma unroll
        for (int o = 0; o < NH; o++) {
            float a = e1b1[o];
            #pragma unroll
            for (int i = 0; i < 16; i++) a = fmaf(e1w1[o * 16 + i], in[i], a);
            h[o] = fmaxf(a, 0.f);
        }
        #pragma unroll
        for (int o = 0; o < NH; o++) {
            float a = e1b2[o];
            #pragma unroll
            for (int j = 0; j < NH; j++) a = fmaf(e1w2[o * NH + j], h[j], a);
            x[o] = a;
        }
        float pv = pos1[(size_t)b * L1_TOK + ll];
        #pragma unroll
        for (int i = 0; i < NH / 2; i++) {
            float w = 3.14159265358979323846f / (float)(i + 1);
            float ang = pv * w;
            x[2 * i]     += __sinf(ang);
            x[2 * i + 1] += __cosf(ang);
        }
    } else {
        float in[NH];
        const float* p = xcT + (size_t)b * NH;
        #pragma unroll
        for (int i = 0; i < NH; i++) in[i] = p[i];
        #pragma unroll
        for (int o = 0; o < NH; o++) {
            float a = ecb1[o];
            #pragma unroll
            for (int i = 0; i < NH; i++) a = fmaf(ecw1[o * NH + i], in[i], a);
            h[o] = fmaxf(a, 0.f);
        }
        #pragma unroll
        for (int o = 0; o < NH; o++) {
            float a = ecb2[o];
            #pragma unroll
            for (int j = 0; j < NH; j++) a = fmaf(ecw2[o * NH + j], h[j], a);
            x[o] = a;
        }
    }
}

// 256 threads, >=2 waves/EU -> VGPR cap 256 (no spill; phase-4 peak ~110).
// LDS 61 KB -> 2 blocks/CU co-resident -> 8 waves/CU.
__global__ __launch_bounds__(NTHREADS, 2) void final_model_kernel(
    const float* __restrict__ x0,  const float* __restrict__ x1,
    const float* __restrict__ pos0,const float* __restrict__ pos1,
    const float* __restrict__ xcT,
    const float* __restrict__ e0w1,const float* __restrict__ e0b1,
    const float* __restrict__ e0w2,const float* __restrict__ e0b2,
    const float* __restrict__ e1w1,const float* __restrict__ e1b1,
    const float* __restrict__ e1w2,const float* __restrict__ e1b2,
    const float* __restrict__ ecw1,const float* __restrict__ ecb1,
    const float* __restrict__ ecw2,const float* __restrict__ ecb2,
    const float* __restrict__ wq,  const float* __restrict__ wk,
    const float* __restrict__ wv,  const float* __restrict__ wo,
    const float* __restrict__ ln1g,const float* __restrict__ ln1b,
    const float* __restrict__ ln2g,const float* __restrict__ ln2b,
    const float* __restrict__ f1w1,const float* __restrict__ f1b1,
    const float* __restrict__ f1w2,const float* __restrict__ f1b2,
    const float* __restrict__ f2w1,const float* __restrict__ f2b1,
    const float* __restrict__ f2w2,const float* __restrict__ f2b2,
    float* __restrict__ out)
{
    const int b   = blockIdx.x;
    const int tid = threadIdx.x;

    __shared__ unsigned Xs[L_TOT * XSTR];   // bf16x2-packed embedded tokens (49.8 KB)
    __shared__ float Cm[NH * NH];           // Gram, later reused as Wb
    __shared__ float T1[NH * NH];
    __shared__ float T2[NH * NH];
    __shared__ float red[4 * 3];

    // Zero the Gram accumulator
    #pragma unroll
    for (int i = tid; i < NH * NH; i += NTHREADS) Cm[i] = 0.f;

    // ---------------- Phase 1: embed all tokens -> LDS (bf16x2) ----------------
    for (int l = tid; l < L_TOT; l += NTHREADS) {
        float xv[NH];
        embed_token(b, l, x0, x1, pos0, pos1, xcT,
                    e0w1, e0b1, e0w2, e0b2, e1w1, e1b1, e1w2, e1b2,
                    ecw1, ecb1, ecw2, ecb2, xv);
        #pragma unroll
        for (int k = 0; k < 16; k++)
            Xs[l * XSTR + k] = pack_bf16x2(xv[2 * k], xv[2 * k + 1]);
    }
    __syncthreads();

    // ---------------- Phase 2: Gram C = sum_l x_l x_l^T ----------------
    // 4 waves, each over a token slice; each lane computes a 4x4 tile (8x8 lane grid).
    {
        const int wvid = tid >> 6, lane = tid & 63;
        const int r = lane >> 3, c = lane & 7;      // tile row/col (features 4r.., 4c..)
        const int lbeg = (L_TOT * wvid) >> 2;
        const int lend = (L_TOT * (wvid + 1)) >> 2;
        float acc[4][4];
        #pragma unroll
        for (int i = 0; i < 4; i++)
            #pragma unroll
            for (int j = 0; j < 4; j++) acc[i][j] = 0.f;

        for (int l = lbeg; l < lend; l++) {
            unsigned wr0 = Xs[l * XSTR + 2 * r], wr1 = Xs[l * XSTR + 2 * r + 1];
            unsigned wc0 = Xs[l * XSTR + 2 * c], wc1 = Xs[l * XSTR + 2 * c + 1];
            float av[4] = {bf_lo(wr0), bf_hi(wr0), bf_lo(wr1), bf_hi(wr1)};
            float bv[4] = {bf_lo(wc0), bf_hi(wc0), bf_lo(wc1), bf_hi(wc1)};
            #pragma unroll
            for (int i = 0; i < 4; i++)
                #pragma unroll
                for (int j = 0; j < 4; j++)
                    acc[i][j] = fmaf(av[i], bv[j], acc[i][j]);
        }
        #pragma unroll
        for (int i = 0; i < 4; i++)
            #pragma unroll
            for (int j = 0; j < 4; j++)
                atomicAdd(&Cm[(4 * r + i) * NH + 4 * c + j], acc[i][j]);
    }
    __syncthreads();

    // ---------------- Phase 3: attention collapse -> Wb (stored in Cm) --------
    // T1 = C @ wk^T
    #pragma unroll
    for (int rr = 0; rr < 4; rr++) {
        int idx = tid + NTHREADS * rr; int i = idx >> 5, g = idx & 31;
        float a = 0.f;
        #pragma unroll
        for (int j = 0; j < NH; j++) a = fmaf(Cm[i * NH + j], wk[g * NH + j], a);
        T1[i * NH + g] = a;
    }
    __syncthreads();
    // T2 = wq @ T1 / sqrt(L)
    const float rsL = 1.0f / sqrtf((float)L_TOT);
    #pragma unroll
    for (int rr = 0; rr < 4; rr++) {
        int idx = tid + NTHREADS * rr; int h = idx >> 5, g = idx & 31;
        float a = 0.f;
        #pragma unroll
        for (int i = 0; i < NH; i++) a = fmaf(wq[h * NH + i], T1[i * NH + g], a);
        T2[h * NH + g] = a * rsL;
    }
    __syncthreads();
    // row softmax of T2
    if (tid < NH) {
        const int h = tid;
        float mx = -1e30f;
        #pragma unroll
        for (int g = 0; g < NH; g++) mx = fmaxf(mx, T2[h * NH + g]);
        float s = 0.f;
        #pragma unroll
        for (int g = 0; g < NH; g++) {
            float e = __expf(T2[h * NH + g] - mx);
            T2[h * NH + g] = e; s += e;
        }
        float inv = 1.f / s;
        #pragma unroll
        for (int g = 0; g < NH; g++) T2[h * NH + g] *= inv;
    }
    __syncthreads();
    // T1 = att @ wv
    #pragma unroll
    for (int rr = 0; rr < 4; rr++) {
        int idx = tid + NTHREADS * rr; int h = idx >> 5, j = idx & 31;
        float a = 0.f;
        #pragma unroll
        for (int g = 0; g < NH; g++) a = fmaf(T2[h * NH + g], wv[g * NH + j], a);
        T1[h * NH + j] = a;
    }
    __syncthreads();
    // Wb (into Cm) = wo @ T1
    #pragma unroll
    for (int rr = 0; rr < 4; rr++) {
        int idx = tid + NTHREADS * rr; int o = idx >> 5, j = idx & 31;
        float a = 0.f;
        #pragma unroll
        for (int h = 0; h < NH; h++) a = fmaf(wo[o * NH + h], T1[h * NH + j], a);
        Cm[o * NH + j] = a;
    }
    __syncthreads();

    // ---------------- Phase 4: per-token pipeline (X from LDS) ----------------
    float s0 = 0.f, s1 = 0.f, sec = 0.f;
    for (int l = tid; l < L_TOT; l += NTHREADS) {
        float x[NH];
        #pragma unroll
        for (int k = 0; k < 16; k++) {
            unsigned w = Xs[l * XSTR + k];
            x[2 * k] = bf_lo(w); x[2 * k + 1] = bf_hi(w);
        }

        // t = Wb @ x + x (residual)
        float t[NH];
        #pragma unroll
        for (int o = 0; o < NH; o++) {
            float a = x[o];
            #pragma unroll
            for (int j = 0; j < NH; j++) a = fmaf(Cm[o * NH + j], x[j], a);
            t[o] = a;
        }
        // LN1 (in place on t)
        float m = 0.f;
        #pragma unroll
        for (int o = 0; o < NH; o++) m += t[o];
        m *= (1.f / 32.f);
        float vv = 0.f;
        #pragma unroll
        for (int o = 0; o < NH; o++) { float d = t[o] - m; vv = fmaf(d, d, vv); }
        vv *= (1.f / 32.f);
        float rs = rsqrtf(vv + 1e-5f);
        #pragma unroll
        for (int o = 0; o < NH; o++) t[o] = (t[o] - m) * rs * ln1g[o] + ln1b[o];

        // FFN1 layer1: u = relu(f1w1 @ t + b1)
        float u[NH];
        #pragma unroll
        for (int o = 0; o < NH; o++) {
            float a = f1b1[o];
            #pragma unroll
            for (int j = 0; j < NH; j++) a = fmaf(f1w1[o * NH + j], t[j], a);
            u[o] = fmaxf(a, 0.f);
        }
        // FFN1 layer2 + residual: t = f1w2 @ u + b2 + x   (x dead after this)
        #pragma unroll
        for (int o = 0; o < NH; o++) {
            float a = f1b2[o] + x[o];
            #pragma unroll
            for (int j = 0; j < NH; j++) a = fmaf(f1w2[o * NH + j], u[j], a);
            t[o] = a;
        }
        // LN2 (in place on t)
        float m2 = 0.f;
        #pragma unroll
        for (int o = 0; o < NH; o++) m2 += t[o];
        m2 *= (1.f / 32.f);
        float v2 = 0.f;
        #pragma unroll
        for (int o = 0; o < NH; o++) { float d = t[o] - m2; v2 = fmaf(d, d, v2); }
        v2 *= (1.f / 32.f);
        float rs2 = rsqrtf(v2 + 1e-5f);
        #pragma unroll
        for (int o = 0; o < NH; o++) t[o] = (t[o] - m2) * rs2 * ln2g[o] + ln2b[o];

        // FFN2 fused to scalar
        float y = f2b2[0];
        #pragma unroll
        for (int o = 0; o < NH; o++) {
            float a = f2b1[o];
            #pragma unroll
            for (int j = 0; j < NH; j++) a = fmaf(f2w1[o * NH + j], t[j], a);
            y = fmaf(f2w2[o], fmaxf(a, 0.f), y);
        }

        if (l < L0_TOK)                 s0 += y;
        else if (l < L0_TOK + L1_TOK)   s1 += y;
        else                            sec += y;
    }

    // ---------------- Segment-mean reduction ----------------
    #pragma unroll
    for (int off = 32; off > 0; off >>= 1) {
        s0  += __shfl_down(s0, off);
        s1  += __shfl_down(s1, off);
        sec += __shfl_down(sec, off);
    }
    const int wid = tid >> 6;
    if ((tid & 63) == 0) {
        red[wid * 3 + 0] = s0;
        red[wid * 3 + 1] = s1;
        red[wid * 3 + 2] = sec;
    }
    __syncthreads();
    if (tid == 0) {
        float a0 = 0.f, a1 = 0.f, a2 = 0.f;
        #pragma unroll
        for (int w = 0; w < 4; w++) {
            a0 += red[w * 3 + 0];
            a1 += red[w * 3 + 1];
            a2 += red[w * 3 + 2];
        }
        out[b] = a0 / (float)L0_TOK + a1 / (float)L1_TOK + a2;
    }
}

extern "C" void kernel_launch(void* const* d_in, const int* in_sizes, int n_in,
                              void* d_out, int out_size, void* d_ws, size_t ws_size,
                              hipStream_t stream)
{
    const float* x0   = (const float*)d_in[0];
    const float* x1   = (const float*)d_in[1];
    const float* pos0 = (const float*)d_in[2];
    const float* pos1 = (const float*)d_in[3];
    const float* xcT  = (const float*)d_in[4];
    const float* e0w1 = (const float*)d_in[5];
    const float* e0b1 = (const float*)d_in[6];
    const float* e0w2 = (const float*)d_in[7];
    const float* e0b2 = (const float*)d_in[8];
    const float* e1w1 = (const float*)d_in[9];
    const float* e1b1 = (const float*)d_in[10];
    const float* e1w2 = (const float*)d_in[11];
    const float* e1b2 = (const float*)d_in[12];
    const float* ecw1 = (const float*)d_in[13];
    const float* ecb1 = (const float*)d_in[14];
    const float* ecw2 = (const float*)d_in[15];
    const float* ecb2 = (const float*)d_in[16];
    const float* wq   = (const float*)d_in[17];
    const float* wk   = (const float*)d_in[18];
    const float* wv   = (const float*)d_in[19];
    const float* wo   = (const float*)d_in[20];
    const float* ln1g = (const float*)d_in[21];
    const float* ln1b = (const float*)d_in[22];
    const float* ln2g = (const float*)d_in[23];
    const float* ln2b = (const float*)d_in[24];
    const float* f1w1 = (const float*)d_in[25];
    const float* f1b1 = (const float*)d_in[26];
    const float* f1w2 = (const float*)d_in[27];
    const float* f1b2 = (const float*)d_in[28];
    const float* f2w1 = (const float*)d_in[29];
    const float* f2b1 = (const float*)d_in[30];
    const float* f2w2 = (const float*)d_in[31];
    const float* f2b2 = (const float*)d_in[32];
    float* out = (float*)d_out;

    const int B = in_sizes[0] / (L0_TOK * 8);

    hipLaunchKernelGGL(final_model_kernel, dim3(B), dim3(NTHREADS), 0, stream,
                       x0, x1, pos0, pos1, xcT,
                       e0w1, e0b1, e0w2, e0b2, e1w1, e1b1, e1w2, e1b2,
                       ecw1, ecb1, ecw2, ecb2, wq, wk, wv, wo,
                       ln1g, ln1b, ln2g, ln2b,
                       f1w1, f1b1, f1w2, f1b2, f2w1, f2b1, f2w2, f2b2,
                       out);
}

// Round 4
// 949.875 us; speedup vs baseline: 5.0114x; 5.0114x over previous
//
#include <hip/hip_runtime.h>
#include <math.h>

#define L0_TOK 365
#define L1_TOK 366
#define L_TOT  732   // 365 + 366 + 1
#define NH     32
#define XSTR   17    // words per token row in LDS (16 bf16x2 + 1 pad)

__device__ __forceinline__ unsigned pack_bf16x2(float a, float b) {
    unsigned ua = __float_as_uint(a), ub = __float_as_uint(b);
    ua = (ua + 0x7fffu + ((ua >> 16) & 1u)) >> 16;
    ub = (ub + 0x7fffu + ((ub >> 16) & 1u)) >> 16;
    return ua | (ub << 16);
}
__device__ __forceinline__ float bf_lo(unsigned w) { return __uint_as_float(w << 16); }
__device__ __forceinline__ float bf_hi(unsigned w) { return __uint_as_float(w & 0xffff0000u); }

// Straight-line embed of token l of batch b -> x[32] (fp32).
// Called from loop-free contexts only (one token per thread) so weight loads
// are NOT loop-invariant -> no LICM hoist -> no spills.
__device__ __forceinline__ void embed_token(
    int b, int l,
    const float* __restrict__ x0, const float* __restrict__ x1,
    const float* __restrict__ pos0, const float* __restrict__ pos1,
    const float* __restrict__ xcT,
    const float* __restrict__ e0w1, const float* __restrict__ e0b1,
    const float* __restrict__ e0w2, const float* __restrict__ e0b2,
    const float* __restrict__ e1w1, const float* __restrict__ e1b1,
    const float* __restrict__ e1w2, const float* __restrict__ e1b2,
    const float* __restrict__ ecw1, const float* __restrict__ ecb1,
    const float* __restrict__ ecw2, const float* __restrict__ ecb2,
    float x[NH])
{
    float h[NH];
    if (l < L0_TOK) {
        float in[8];
        const float4* p = (const float4*)(x0 + ((size_t)b * L0_TOK + l) * 8);
        float4 v0 = p[0], v1 = p[1];
        in[0]=v0.x; in[1]=v0.y; in[2]=v0.z; in[3]=v0.w;
        in[4]=v1.x; in[5]=v1.y; in[6]=v1.z; in[7]=v1.w;
        #pragma unroll
        for (int o = 0; o < NH; o++) {
            float a = e0b1[o];
            #pragma unroll
            for (int i = 0; i < 8; i++) a = fmaf(e0w1[o * 8 + i], in[i], a);
            h[o] = fmaxf(a, 0.f);
        }
        #pragma unroll
        for (int o = 0; o < NH; o++) {
            float a = e0b2[o];
            #pragma unroll
            for (int j = 0; j < NH; j++) a = fmaf(e0w2[o * NH + j], h[j], a);
            x[o] = a;
        }
        float pv = pos0[(size_t)b * L0_TOK + l];
        #pragma unroll
        for (int i = 0; i < NH / 2; i++) {
            float w = 3.14159265358979323846f / (float)(i + 1);
            float ang = pv * w;
            x[2 * i]     += __sinf(ang);
            x[2 * i + 1] += __cosf(ang);
        }
    } else if (l < L0_TOK + L1_TOK) {
        int ll = l - L0_TOK;
        float in[16];
        const float4* p = (const float4*)(x1 + ((size_t)b * L1_TOK + ll) * 16);
        #pragma unroll
        for (int q = 0; q < 4; q++) {
            float4 v = p[q];
            in[4*q+0]=v.x; in[4*q+1]=v.y; in[4*q+2]=v.z; in[4*q+3]=v.w;
        }
        #pragma unroll
        for (int o = 0; o < NH; o++) {
            float a = e1b1[o];
            #pragma unroll
            for (int i = 0; i < 16; i++) a = fmaf(e1w1[o * 16 + i], in[i], a);
            h[o] = fmaxf(a, 0.f);
        }
        #pragma unroll
        for (int o = 0; o < NH; o++) {
            float a = e1b2[o];
            #pragma unroll
            for (int j = 0; j < NH; j++) a = fmaf(e1w2[o * NH + j], h[j], a);
            x[o] = a;
        }
        float pv = pos1[(size_t)b * L1_TOK + ll];
        #pragma unroll
        for (int i = 0; i < NH / 2; i++) {
            float w = 3.14159265358979323846f / (float)(i + 1);
            float ang = pv * w;
            x[2 * i]     += __sinf(ang);
            x[2 * i + 1] += __cosf(ang);
        }
    } else {
        float in[NH];
        const float* p = xcT + (size_t)b * NH;
        #pragma unroll
        for (int i = 0; i < NH; i++) in[i] = p[i];
        #pragma unroll
        for (int o = 0; o < NH; o++) {
            float a = ecb1[o];
            #pragma unroll
            for (int i = 0; i < NH; i++) a = fmaf(ecw1[o * NH + i], in[i], a);
            h[o] = fmaxf(a, 0.f);
        }
        #pragma unroll
        for (int o = 0; o < NH; o++) {
            float a = ecb2[o];
            #pragma unroll
            for (int j = 0; j < NH; j++) a = fmaf(ecw2[o * NH + j], h[j], a);
            x[o] = a;
        }
    }
}

// =================== Kernel A: embed + Gram + attention collapse ===========
// 768 threads: one token per thread (no loop over weight loads).
__global__ __launch_bounds__(768) void kernelA(
    const float* __restrict__ x0,  const float* __restrict__ x1,
    const float* __restrict__ pos0,const float* __restrict__ pos1,
    const float* __restrict__ xcT,
    const float* __restrict__ e0w1,const float* __restrict__ e0b1,
    const float* __restrict__ e0w2,const float* __restrict__ e0b2,
    const float* __restrict__ e1w1,const float* __restrict__ e1b1,
    const float* __restrict__ e1w2,const float* __restrict__ e1b2,
    const float* __restrict__ ecw1,const float* __restrict__ ecb1,
    const float* __restrict__ ecw2,const float* __restrict__ ecb2,
    const float* __restrict__ wq,  const float* __restrict__ wk,
    const float* __restrict__ wv,  const float* __restrict__ wo,
    float* __restrict__ wbout)                   // [B][1024]
{
    const int b   = blockIdx.x;
    const int tid = threadIdx.x;

    __shared__ unsigned Xs[L_TOT * XSTR];   // 49.8 KB
    __shared__ float Cm[NH * NH];
    __shared__ float T1[NH * NH];
    __shared__ float T2[NH * NH];

    if (tid < NH * NH + 768 && tid >= 768) {}  // no-op
    for (int i = tid; i < NH * NH; i += 768) Cm[i] = 0.f;

    // ---- embed: one token per thread, straight-line ----
    if (tid < L_TOT) {
        float xv[NH];
        embed_token(b, tid, x0, x1, pos0, pos1, xcT,
                    e0w1, e0b1, e0w2, e0b2, e1w1, e1b1, e1w2, e1b2,
                    ecw1, ecb1, ecw2, ecb2, xv);
        #pragma unroll
        for (int k = 0; k < 16; k++)
            Xs[tid * XSTR + k] = pack_bf16x2(xv[2 * k], xv[2 * k + 1]);
    }
    __syncthreads();

    // ---- Gram C = sum_l x_l x_l^T : 12 waves x 61 tokens, 4x4 tiles ----
    {
        const int wvid = tid >> 6, lane = tid & 63;
        const int r = lane >> 3, c = lane & 7;
        const int lbeg = 61 * wvid;
        const int lend = 61 * (wvid + 1);
        float acc[4][4];
        #pragma unroll
        for (int i = 0; i < 4; i++)
            #pragma unroll
            for (int j = 0; j < 4; j++) acc[i][j] = 0.f;
        for (int l = lbeg; l < lend; l++) {
            unsigned wr0 = Xs[l * XSTR + 2 * r], wr1 = Xs[l * XSTR + 2 * r + 1];
            unsigned wc0 = Xs[l * XSTR + 2 * c], wc1 = Xs[l * XSTR + 2 * c + 1];
            float av[4] = {bf_lo(wr0), bf_hi(wr0), bf_lo(wr1), bf_hi(wr1)};
            float bv[4] = {bf_lo(wc0), bf_hi(wc0), bf_lo(wc1), bf_hi(wc1)};
            #pragma unroll
            for (int i = 0; i < 4; i++)
                #pragma unroll
                for (int j = 0; j < 4; j++)
                    acc[i][j] = fmaf(av[i], bv[j], acc[i][j]);
        }
        #pragma unroll
        for (int i = 0; i < 4; i++)
            #pragma unroll
            for (int j = 0; j < 4; j++)
                atomicAdd(&Cm[(4 * r + i) * NH + 4 * c + j], acc[i][j]);
    }
    __syncthreads();

    // ---- attention collapse: Wb = wo @ softmax(wq C wk^T / sqrt(L)) @ wv ----
    for (int idx = tid; idx < NH * NH; idx += 768) {
        int i = idx >> 5, g = idx & 31;
        float a = 0.f;
        #pragma unroll
        for (int j = 0; j < NH; j++) a = fmaf(Cm[i * NH + j], wk[g * NH + j], a);
        T1[i * NH + g] = a;
    }
    __syncthreads();
    const float rsL = 1.0f / sqrtf((float)L_TOT);
    for (int idx = tid; idx < NH * NH; idx += 768) {
        int h = idx >> 5, g = idx & 31;
        float a = 0.f;
        #pragma unroll
        for (int i = 0; i < NH; i++) a = fmaf(wq[h * NH + i], T1[i * NH + g], a);
        T2[h * NH + g] = a * rsL;
    }
    __syncthreads();
    if (tid < NH) {
        const int h = tid;
        float mx = -1e30f;
        #pragma unroll
        for (int g = 0; g < NH; g++) mx = fmaxf(mx, T2[h * NH + g]);
        float s = 0.f;
        #pragma unroll
        for (int g = 0; g < NH; g++) {
            float e = __expf(T2[h * NH + g] - mx);
            T2[h * NH + g] = e; s += e;
        }
        float inv = 1.f / s;
        #pragma unroll
        for (int g = 0; g < NH; g++) T2[h * NH + g] *= inv;
    }
    __syncthreads();
    for (int idx = tid; idx < NH * NH; idx += 768) {
        int h = idx >> 5, j = idx & 31;
        float a = 0.f;
        #pragma unroll
        for (int g = 0; g < NH; g++) a = fmaf(T2[h * NH + g], wv[g * NH + j], a);
        T1[h * NH + j] = a;
    }
    __syncthreads();
    for (int idx = tid; idx < NH * NH; idx += 768) {
        int o = idx >> 5, j = idx & 31;
        float a = 0.f;
        #pragma unroll
        for (int h = 0; h < NH; h++) a = fmaf(wo[o * NH + h], T1[h * NH + j], a);
        wbout[(size_t)b * (NH * NH) + o * NH + j] = a;
    }
}

// =================== Kernel B: per-token pipeline ==========================
// grid (B, 3): chunk c covers tokens [c*244, c*244+244); one token per thread.
__global__ __launch_bounds__(256) void kernelB(
    const float* __restrict__ x0,  const float* __restrict__ x1,
    const float* __restrict__ pos0,const float* __restrict__ pos1,
    const float* __restrict__ xcT,
    const float* __restrict__ e0w1,const float* __restrict__ e0b1,
    const float* __restrict__ e0w2,const float* __restrict__ e0b2,
    const float* __restrict__ e1w1,const float* __restrict__ e1b1,
    const float* __restrict__ e1w2,const float* __restrict__ e1b2,
    const float* __restrict__ ecw1,const float* __restrict__ ecb1,
    const float* __restrict__ ecw2,const float* __restrict__ ecb2,
    const float* __restrict__ wbin,              // [B][1024]
    const float* __restrict__ ln1g,const float* __restrict__ ln1b,
    const float* __restrict__ ln2g,const float* __restrict__ ln2b,
    const float* __restrict__ f1w1,const float* __restrict__ f1b1,
    const float* __restrict__ f1w2,const float* __restrict__ f1b2,
    const float* __restrict__ f2w1,const float* __restrict__ f2b1,
    const float* __restrict__ f2w2,const float* __restrict__ f2b2,
    float* __restrict__ part)                    // [B][3 chunks][3 segs]
{
    const int b   = blockIdx.x;
    const int c   = blockIdx.y;
    const int tid = threadIdx.x;
    const int l   = c * 244 + tid;
    const bool active = (tid < 244);

    __shared__ float red[4 * 3];

    float y = 0.f;
    int seg = 2;
    if (active) {
        float x[NH];
        embed_token(b, l, x0, x1, pos0, pos1, xcT,
                    e0w1, e0b1, e0w2, e0b2, e1w1, e1b1, e1w2, e1b2,
                    ecw1, ecb1, ecw2, ecb2, x);

        const float* wb = wbin + (size_t)b * (NH * NH);
        float t[NH];
        #pragma unroll
        for (int o = 0; o < NH; o++) {
            float a = x[o];
            #pragma unroll
            for (int j = 0; j < NH; j++) a = fmaf(wb[o * NH + j], x[j], a);
            t[o] = a;
        }
        // LN1
        float m = 0.f;
        #pragma unroll
        for (int o = 0; o < NH; o++) m += t[o];
        m *= (1.f / 32.f);
        float vv = 0.f;
        #pragma unroll
        for (int o = 0; o < NH; o++) { float d = t[o] - m; vv = fmaf(d, d, vv); }
        vv *= (1.f / 32.f);
        float rs = rsqrtf(vv + 1e-5f);
        #pragma unroll
        for (int o = 0; o < NH; o++) t[o] = (t[o] - m) * rs * ln1g[o] + ln1b[o];

        // FFN1
        float u[NH];
        #pragma unroll
        for (int o = 0; o < NH; o++) {
            float a = f1b1[o];
            #pragma unroll
            for (int j = 0; j < NH; j++) a = fmaf(f1w1[o * NH + j], t[j], a);
            u[o] = fmaxf(a, 0.f);
        }
        #pragma unroll
        for (int o = 0; o < NH; o++) {
            float a = f1b2[o] + x[o];
            #pragma unroll
            for (int j = 0; j < NH; j++) a = fmaf(f1w2[o * NH + j], u[j], a);
            t[o] = a;
        }
        // LN2
        float m2 = 0.f;
        #pragma unroll
        for (int o = 0; o < NH; o++) m2 += t[o];
        m2 *= (1.f / 32.f);
        float v2 = 0.f;
        #pragma unroll
        for (int o = 0; o < NH; o++) { float d = t[o] - m2; v2 = fmaf(d, d, v2); }
        v2 *= (1.f / 32.f);
        float rs2 = rsqrtf(v2 + 1e-5f);
        #pragma unroll
        for (int o = 0; o < NH; o++) t[o] = (t[o] - m2) * rs2 * ln2g[o] + ln2b[o];

        // FFN2 -> scalar
        float yy = f2b2[0];
        #pragma unroll
        for (int o = 0; o < NH; o++) {
            float a = f2b1[o];
            #pragma unroll
            for (int j = 0; j < NH; j++) a = fmaf(f2w1[o * NH + j], t[j], a);
            yy = fmaf(f2w2[o], fmaxf(a, 0.f), yy);
        }
        y = yy;
        seg = (l < L0_TOK) ? 0 : (l < L0_TOK + L1_TOK ? 1 : 2);
    }

    float s0 = (seg == 0 && active) ? y : 0.f;
    float s1 = (seg == 1 && active) ? y : 0.f;
    float sc = (seg == 2 && active) ? y : 0.f;
    #pragma unroll
    for (int off = 32; off > 0; off >>= 1) {
        s0 += __shfl_down(s0, off);
        s1 += __shfl_down(s1, off);
        sc += __shfl_down(sc, off);
    }
    const int wid = tid >> 6;
    if ((tid & 63) == 0) {
        red[wid * 3 + 0] = s0;
        red[wid * 3 + 1] = s1;
        red[wid * 3 + 2] = sc;
    }
    __syncthreads();
    if (tid == 0) {
        float a0 = 0.f, a1 = 0.f, a2 = 0.f;
        #pragma unroll
        for (int w = 0; w < 4; w++) {
            a0 += red[w * 3 + 0];
            a1 += red[w * 3 + 1];
            a2 += red[w * 3 + 2];
        }
        float* p = part + ((size_t)b * 3 + c) * 3;
        p[0] = a0; p[1] = a1; p[2] = a2;
    }
}

// =================== Kernel C: final reduction =============================
__global__ __launch_bounds__(256) void kernelC(
    const float* __restrict__ part, float* __restrict__ out, int B)
{
    int b = blockIdx.x * 256 + threadIdx.x;
    if (b >= B) return;
    const float* p = part + (size_t)b * 9;
    float a0 = p[0] + p[3] + p[6];
    float a1 = p[1] + p[4] + p[7];
    float a2 = p[2] + p[5] + p[8];
    out[b] = a0 / (float)L0_TOK + a1 / (float)L1_TOK + a2;
}

extern "C" void kernel_launch(void* const* d_in, const int* in_sizes, int n_in,
                              void* d_out, int out_size, void* d_ws, size_t ws_size,
                              hipStream_t stream)
{
    const float* x0   = (const float*)d_in[0];
    const float* x1   = (const float*)d_in[1];
    const float* pos0 = (const float*)d_in[2];
    const float* pos1 = (const float*)d_in[3];
    const float* xcT  = (const float*)d_in[4];
    const float* e0w1 = (const float*)d_in[5];
    const float* e0b1 = (const float*)d_in[6];
    const float* e0w2 = (const float*)d_in[7];
    const float* e0b2 = (const float*)d_in[8];
    const float* e1w1 = (const float*)d_in[9];
    const float* e1b1 = (const float*)d_in[10];
    const float* e1w2 = (const float*)d_in[11];
    const float* e1b2 = (const float*)d_in[12];
    const float* ecw1 = (const float*)d_in[13];
    const float* ecb1 = (const float*)d_in[14];
    const float* ecw2 = (const float*)d_in[15];
    const float* ecb2 = (const float*)d_in[16];
    const float* wq   = (const float*)d_in[17];
    const float* wk   = (const float*)d_in[18];
    const float* wv   = (const float*)d_in[19];
    const float* wo   = (const float*)d_in[20];
    const float* ln1g = (const float*)d_in[21];
    const float* ln1b = (const float*)d_in[22];
    const float* ln2g = (const float*)d_in[23];
    const float* ln2b = (const float*)d_in[24];
    const float* f1w1 = (const float*)d_in[25];
    const float* f1b1 = (const float*)d_in[26];
    const float* f1w2 = (const float*)d_in[27];
    const float* f1b2 = (const float*)d_in[28];
    const float* f2w1 = (const float*)d_in[29];
    const float* f2b1 = (const float*)d_in[30];
    const float* f2w2 = (const float*)d_in[31];
    const float* f2b2 = (const float*)d_in[32];
    float* out = (float*)d_out;

    const int B = in_sizes[0] / (L0_TOK * 8);

    float* wsf  = (float*)d_ws;
    float* wb   = wsf;                                  // B*1024 floats
    float* part = wsf + (size_t)B * (NH * NH);          // B*9 floats

    hipLaunchKernelGGL(kernelA, dim3(B), dim3(768), 0, stream,
                       x0, x1, pos0, pos1, xcT,
                       e0w1, e0b1, e0w2, e0b2, e1w1, e1b1, e1w2, e1b2,
                       ecw1, ecb1, ecw2, ecb2, wq, wk, wv, wo, wb);

    hipLaunchKernelGGL(kernelB, dim3(B, 3), dim3(256), 0, stream,
                       x0, x1, pos0, pos1, xcT,
                       e0w1, e0b1, e0w2, e0b2, e1w1, e1b1, e1w2, e1b2,
                       ecw1, ecb1, ecw2, ecb2, wb,
                       ln1g, ln1b, ln2g, ln2b,
                       f1w1, f1b1, f1w2, f1b2, f2w1, f2b1, f2w2, f2b2,
                       part);

    hipLaunchKernelGGL(kernelC, dim3((B + 255) / 256), dim3(256), 0, stream,
                       part, out, B);
}